// Round 3
// baseline (1366.907 us; speedup 1.0000x reference)
//
#include <hip/hip_runtime.h>

#define NEGV -1e30f
static constexpr int BATCH = 64;
static constexpr int NN = 512;
static constexpr int MM = 512;
static constexpr int NM = NN * MM;
static constexpr size_t TOTAL = (size_t)BATCH * NM;

// ---------------------------------------------------------------------------
// K1: wavefront DP, one 64-lane wave per (batch, direction) problem.
// Lane t owns rows [8t, 8t+8). Diagonal state (k-1, k-2) in registers; only
// cross-lane dependency is lane t-1's row-7 values -> __shfl_up. No LDS, no
// barriers. k-loop unrolled x4 so all array indices are compile-time
// (phase = (kk - r) & 3), keeping everything in VGPRs.
// D is read as float4 column-groups with 4-diagonal prefetch slack.
// __launch_bounds__(64,1): full 512-VGPR budget (R1's 52-VGPR spill fix).
// ---------------------------------------------------------------------------
template <int DIR>
__device__ __forceinline__ void dp_run(const float* __restrict__ Db,
                                       float* __restrict__ R, int lane) {
    const int i0 = lane * 8;

    float p1[8], p2[8];        // R on diagonals k-1 / k-2 for my 8 rows
    float dcur[8][4], dnxt[8][4];  // D column-group being consumed / in flight
    float stv[8][4];           // store staging: 4-column groups per row
    float np[8];

#pragma unroll
    for (int r = 0; r < 8; ++r) {
        p1[r] = NEGV; p2[r] = NEGV;
#pragma unroll
        for (int c = 0; c < 4; ++c) { dcur[r][c] = 0.f; dnxt[r][c] = 0.f; stv[r][c] = 0.f; }
    }

    // preload first column group (cols 0..3) of each owned row
#pragma unroll
    for (int r = 0; r < 8; ++r) {
        const int i = i0 + r;
        if (DIR) {
            const float4 v = *(const float4*)(Db + (NM - 4 - i * MM));
            dnxt[r][0] = v.w; dnxt[r][1] = v.z; dnxt[r][2] = v.y; dnxt[r][3] = v.x;
        } else {
            const float4 v = *(const float4*)(Db + i * MM);
            dnxt[r][0] = v.x; dnxt[r][1] = v.y; dnxt[r][2] = v.z; dnxt[r][3] = v.w;
        }
    }

    for (int kb = 0; kb < NN + MM; kb += 4) {
#pragma unroll
        for (int kk = 0; kk < 4; ++kk) {
            const int k = kb + kk;

            // boundary values from lane-1's last row (diag k-1 and k-2)
            const float up_s = __shfl_up(p1[7], 1);
            const float dg_s = __shfl_up(p2[7], 1);
            const float up0 = (lane == 0) ? NEGV : up_s;
            const float dg0 = (lane == 0) ? NEGV : dg_s;

#pragma unroll
            for (int r = 0; r < 8; ++r) {
                const int i = i0 + r;
                const int j = k - i;
                constexpr_int:;
                const int ph = (kk - r) & 3;     // == (k - i) & 3, compile-time
                const bool act = (j >= 0) && (j < MM);

                if (ph == 0) {
                    if (act) {
                        // start a new column group: consume prefetched, refill
#pragma unroll
                        for (int c = 0; c < 4; ++c) dcur[r][c] = dnxt[r][c];
                        if (j + 4 < MM) {
                            if (DIR) {
                                const float4 v = *(const float4*)(Db + (NM - 8 - i * MM - j));
                                dnxt[r][0] = v.w; dnxt[r][1] = v.z;
                                dnxt[r][2] = v.y; dnxt[r][3] = v.x;
                            } else {
                                const float4 v = *(const float4*)(Db + i * MM + j + 4);
                                dnxt[r][0] = v.x; dnxt[r][1] = v.y;
                                dnxt[r][2] = v.z; dnxt[r][3] = v.w;
                            }
                        }
                    }
                }

                float val = NEGV;
                if (act) {
                    const float upsrc = (r == 0) ? up0 : p1[r - 1];
                    const float dgsrc = (r == 0) ? dg0 : p2[r - 1];
                    const float dg = (i == 0) ? ((j == 0) ? 0.f : NEGV)
                                              : ((j == 0) ? NEGV : dgsrc);
                    const float up = (i == 0) ? NEGV : upsrc;
                    const float lf = (j == 0) ? NEGV : p1[r];
                    const float m = fmaxf(fmaxf(dg, up), lf);
                    // one arg equals m -> log argument in [1,3]: fast math safe
                    val = dcur[r][ph] + m +
                        __logf(__expf(dg - m) + __expf(up - m) + __expf(lf - m));
                    stv[r][ph] = val;
                    if (ph == 3) {
                        // full 4-column group -> one aligned float4 store
                        if (DIR) {
                            const float4 v = make_float4(stv[r][3], stv[r][2],
                                                         stv[r][1], stv[r][0]);
                            *(float4*)(R + (NM - 1 - i * MM - j)) = v;
                        } else {
                            const float4 v = make_float4(stv[r][0], stv[r][1],
                                                         stv[r][2], stv[r][3]);
                            *(float4*)(R + (i * MM + j - 3)) = v;
                        }
                    }
                }
                np[r] = val;
            }
#pragma unroll
            for (int r = 0; r < 8; ++r) { p2[r] = p1[r]; p1[r] = np[r]; }
        }
    }
}

__global__ __launch_bounds__(64, 1) void dp_kernel(const float* __restrict__ D,
                                                   float* __restrict__ Rf,
                                                   float* __restrict__ Rb) {
    const int blk = blockIdx.x;
    const int b = blk & (BATCH - 1);
    const int dir = blk >> 6;                 // wave-uniform (SGPR branch)
    const float* __restrict__ Db = D + (size_t)b * NM;
    const int lane = threadIdx.x;
    if (dir) {
        dp_run<1>(Db, Rb + (size_t)b * NM, lane);
    } else {
        dp_run<0>(Db, Rf + (size_t)b * NM, lane);
    }
}

// ---------------------------------------------------------------------------
// block-level max reduction (256 threads)
// ---------------------------------------------------------------------------
__device__ inline float blockMax256(float v) {
    __shared__ float sm[256];
    sm[threadIdx.x] = v;
    __syncthreads();
    for (int s = 128; s > 0; s >>= 1) {
        if ((int)threadIdx.x < s)
            sm[threadIdx.x] = fmaxf(sm[threadIdx.x], sm[threadIdx.x + s]);
        __syncthreads();
    }
    return sm[0];
}

// K2: logit = f + b - d (in place into out, which holds f), per-block max
__global__ __launch_bounds__(256) void logit_kernel(const float4* __restrict__ D,
                                                    const float4* __restrict__ Rb,
                                                    float4* __restrict__ out,
                                                    float* __restrict__ partial) {
    const size_t n4 = TOTAL / 4;
    float mx = NEGV;
    const size_t stride = (size_t)gridDim.x * blockDim.x;
    for (size_t idx = (size_t)blockIdx.x * blockDim.x + threadIdx.x; idx < n4;
         idx += stride) {
        float4 f = out[idx], bb = Rb[idx], d = D[idx];
        float4 v = make_float4(f.x + bb.x - d.x, f.y + bb.y - d.y,
                               f.z + bb.z - d.z, f.w + bb.w - d.w);
        out[idx] = v;
        mx = fmaxf(mx, fmaxf(fmaxf(v.x, v.y), fmaxf(v.z, v.w)));
    }
    float bm = blockMax256(mx);
    if (threadIdx.x == 0) partial[blockIdx.x] = bm;
}

// K3: reduce partials to one scalar
__global__ __launch_bounds__(256) void finalmax_kernel(const float* __restrict__ partial,
                                                       int n,
                                                       float* __restrict__ outmax) {
    float mx = NEGV;
    for (int i = threadIdx.x; i < n; i += 256) mx = fmaxf(mx, partial[i]);
    float bm = blockMax256(mx);
    if (threadIdx.x == 0) *outmax = bm;
}

// K4: out -= max  (GAMMA = T = 1)
__global__ __launch_bounds__(256) void sub_kernel(float4* __restrict__ out,
                                                  const float* __restrict__ maxp) {
    const float mx = *maxp;
    const size_t n4 = TOTAL / 4;
    const size_t stride = (size_t)gridDim.x * blockDim.x;
    for (size_t idx = (size_t)blockIdx.x * blockDim.x + threadIdx.x; idx < n4;
         idx += stride) {
        float4 v = out[idx];
        v.x -= mx; v.y -= mx; v.z -= mx; v.w -= mx;
        out[idx] = v;
    }
}

extern "C" void kernel_launch(void* const* d_in, const int* in_sizes, int n_in,
                              void* d_out, int out_size, void* d_ws, size_t ws_size,
                              hipStream_t stream) {
    const float* D = (const float*)d_in[0];
    float* out = (float*)d_out;      // holds Rf after K1, logit after K2
    float* Rb = (float*)d_ws;        // 64 MB backward DP result
    float* partial = Rb + TOTAL;     // 2048 floats
    float* maxp = partial + 2048;    // 1 float

    dp_kernel<<<128, 64, 0, stream>>>(D, out, Rb);
    logit_kernel<<<2048, 256, 0, stream>>>((const float4*)D, (const float4*)Rb,
                                           (float4*)out, partial);
    finalmax_kernel<<<1, 256, 0, stream>>>(partial, 2048, maxp);
    sub_kernel<<<2048, 256, 0, stream>>>((float4*)out, maxp);
}

// Round 4
// 701.743 us; speedup vs baseline: 1.9479x; 1.9479x over previous
//
#include <hip/hip_runtime.h>

#define NEGV -1e30f
static constexpr int BATCH = 64;
static constexpr int NN = 512;
static constexpr int MM = 512;
static constexpr int NM = NN * MM;
static constexpr size_t TOTAL = (size_t)BATCH * NM;

// lane n <- lane n-1 (whole-wave shift right by 1), 1 VALU op, no LDS.
__device__ __forceinline__ float wave_shr1(float x) {
    int y = __builtin_amdgcn_mov_dpp(__float_as_int(x), 0x138, 0xf, 0xf, true);
    return __int_as_float(y);
}

// compile-time float4 component select (folds after macro expansion)
#define F4C(v, c) ((c) == 0 ? (v).x : (c) == 1 ? (v).y : (c) == 2 ? (v).z : (v).w)

// ---------------------------------------------------------------------------
// K1: wavefront DP, one 64-lane wave per (batch, direction) problem.
// Lane t owns rows [8t, 8t+8). ALL state in individually named registers
// (no arrays -> no failed-SROA scratch, the R1/R2 killer). Cross-lane dep via
// DPP wave_shr1. Branchless interior: out-of-range cells compute harmless
// ~NEGV garbage (never feeds valid cells); stores guarded, loads clamped.
// D staged as per-row float4 groups, swapped every 4 diagonals (4-diag slack).
// ---------------------------------------------------------------------------
template <int DIR>
__device__ __forceinline__ void dp_run(const float* __restrict__ Db,
                                       float* __restrict__ Rp, int lane) {
    const int i0 = lane * 8;
    const bool l0 = (lane == 0);
    const float dgb0 = l0 ? 0.f : NEGV;   // diag boundary value for row 0 at j==0

#define PTRS(r) \
    const float* ldp_##r = DIR ? (Db + (size_t)(NM - 1) - (size_t)(i0 + r) * MM) \
                               : (Db + (size_t)(i0 + r) * MM); \
    float* stp_##r = DIR ? (Rp + (size_t)(NM - 1) - (size_t)(i0 + r) * MM) \
                         : (Rp + (size_t)(i0 + r) * MM);
    PTRS(0) PTRS(1) PTRS(2) PTRS(3) PTRS(4) PTRS(5) PTRS(6) PTRS(7)

// load float4 covering logical cols [jc, jc+3] of row r (clamped)
#define LOADG(r, dst, jgexpr) do { \
        int jc_ = (jgexpr); \
        jc_ = jc_ < 0 ? 0 : jc_; jc_ = jc_ > (MM - 4) ? (MM - 4) : jc_; \
        if (DIR) { const float4 t_ = *(const float4*)(ldp_##r - jc_ - 3); \
                   dst = make_float4(t_.w, t_.z, t_.y, t_.x); } \
        else     { dst = *(const float4*)(ldp_##r + jc_); } \
    } while (0)

#define INIT(r) \
    float p1_##r = NEGV, p2_##r = NEGV, p3_##r = NEGV, np_##r = NEGV; \
    float4 dc_##r, dn_##r; \
    LOADG(r, dn_##r, 0); dc_##r = dn_##r;
    INIT(0) INIT(1) INIT(2) INIT(3) INIT(4) INIT(5) INIT(6) INIT(7)

// consume prefetched group, issue next load (rows hitting phase 0 this diag)
#define SWAPLOAD(r) do { dc_##r = dn_##r; LOADG(r, dn_##r, jj - (r) + 4); } while (0)

// one DP cell for row r at diagonal kb+KK
#define CELL(r, KK, DGIN, UPIN, DGB) do { \
        const int j_ = jj - (r); \
        const bool jz_ = (j_ == 0); \
        const float dg_ = jz_ ? (DGB) : (DGIN); \
        const float up_ = (UPIN); \
        const float lf_ = jz_ ? NEGV : p1_##r; \
        const float m_  = fmaxf(fmaxf(dg_, up_), lf_); \
        const float mn_ = fminf(fminf(dg_, up_), lf_); \
        const float md_ = __builtin_amdgcn_fmed3f(dg_, up_, lf_); \
        const float s_  = 1.f + __expf(mn_ - m_) + __expf(md_ - m_); \
        np_##r = F4C(dc_##r, ((KK) - (r)) & 3) + m_ + __logf(s_); \
    } while (0)

// guarded float4 store of the completed 4-col group (rows hitting phase 3)
#define STORE(r) do { \
        const int j_ = jj - (r); \
        if (j_ >= 3 && j_ < MM) { \
            if (DIR) *(float4*)(stp_##r - j_) = \
                make_float4(np_##r, p1_##r, p2_##r, p3_##r); \
            else     *(float4*)(stp_##r + j_ - 3) = \
                make_float4(p3_##r, p2_##r, p1_##r, np_##r); \
        } \
    } while (0)

#define SHIFT(r) do { p3_##r = p2_##r; p2_##r = p1_##r; p1_##r = np_##r; } while (0)

// one diagonal: KK = k & 3; LA/LB = rows at phase 0; SA/SB = rows at phase 3
#define STEP(KK, LA, LB, SA, SB) do { \
        const int jj = kbj + (KK); \
        SWAPLOAD(LA); SWAPLOAD(LB); \
        const float ups_ = wave_shr1(p1_7); \
        const float dgs_ = wave_shr1(p2_7); \
        const float up0r = l0 ? NEGV : ups_; \
        const float dg0r = l0 ? NEGV : dgs_; \
        CELL(0, KK, dg0r, up0r, dgb0); \
        CELL(1, KK, p2_0, p1_0, NEGV); \
        CELL(2, KK, p2_1, p1_1, NEGV); \
        CELL(3, KK, p2_2, p1_2, NEGV); \
        CELL(4, KK, p2_3, p1_3, NEGV); \
        CELL(5, KK, p2_4, p1_4, NEGV); \
        CELL(6, KK, p2_5, p1_5, NEGV); \
        CELL(7, KK, p2_6, p1_6, NEGV); \
        STORE(SA); STORE(SB); \
        SHIFT(0); SHIFT(1); SHIFT(2); SHIFT(3); \
        SHIFT(4); SHIFT(5); SHIFT(6); SHIFT(7); \
    } while (0)

    for (int kb = 0; kb < NN + MM; kb += 4) {
        const int kbj = kb - i0;
        STEP(0, 0, 4, 1, 5);
        STEP(1, 1, 5, 2, 6);
        STEP(2, 2, 6, 3, 7);
        STEP(3, 3, 7, 0, 4);
    }

#undef PTRS
#undef LOADG
#undef INIT
#undef SWAPLOAD
#undef CELL
#undef STORE
#undef SHIFT
#undef STEP
}

__global__ __launch_bounds__(64, 1) void dp_kernel(const float* __restrict__ D,
                                                   float* __restrict__ Rf,
                                                   float* __restrict__ Rb) {
    const int blk = blockIdx.x;
    const int b = blk & (BATCH - 1);
    const int dir = blk >> 6;                 // wave-uniform (SGPR branch)
    const float* __restrict__ Db = D + (size_t)b * NM;
    const int lane = threadIdx.x;
    if (dir) {
        dp_run<1>(Db, Rb + (size_t)b * NM, lane);
    } else {
        dp_run<0>(Db, Rf + (size_t)b * NM, lane);
    }
}

// ---------------------------------------------------------------------------
// block-level max reduction (256 threads)
// ---------------------------------------------------------------------------
__device__ inline float blockMax256(float v) {
    __shared__ float sm[256];
    sm[threadIdx.x] = v;
    __syncthreads();
    for (int s = 128; s > 0; s >>= 1) {
        if ((int)threadIdx.x < s)
            sm[threadIdx.x] = fmaxf(sm[threadIdx.x], sm[threadIdx.x + s]);
        __syncthreads();
    }
    return sm[0];
}

// K2: logit = f + b - d (in place into out, which holds f), per-block max
__global__ __launch_bounds__(256) void logit_kernel(const float4* __restrict__ D,
                                                    const float4* __restrict__ Rb,
                                                    float4* __restrict__ out,
                                                    float* __restrict__ partial) {
    const size_t n4 = TOTAL / 4;
    float mx = NEGV;
    const size_t stride = (size_t)gridDim.x * blockDim.x;
    for (size_t idx = (size_t)blockIdx.x * blockDim.x + threadIdx.x; idx < n4;
         idx += stride) {
        float4 f = out[idx], bb = Rb[idx], d = D[idx];
        float4 v = make_float4(f.x + bb.x - d.x, f.y + bb.y - d.y,
                               f.z + bb.z - d.z, f.w + bb.w - d.w);
        out[idx] = v;
        mx = fmaxf(mx, fmaxf(fmaxf(v.x, v.y), fmaxf(v.z, v.w)));
    }
    float bm = blockMax256(mx);
    if (threadIdx.x == 0) partial[blockIdx.x] = bm;
}

// K3: reduce partials to one scalar
__global__ __launch_bounds__(256) void finalmax_kernel(const float* __restrict__ partial,
                                                       int n,
                                                       float* __restrict__ outmax) {
    float mx = NEGV;
    for (int i = threadIdx.x; i < n; i += 256) mx = fmaxf(mx, partial[i]);
    float bm = blockMax256(mx);
    if (threadIdx.x == 0) *outmax = bm;
}

// K4: out -= max  (GAMMA = T = 1)
__global__ __launch_bounds__(256) void sub_kernel(float4* __restrict__ out,
                                                  const float* __restrict__ maxp) {
    const float mx = *maxp;
    const size_t n4 = TOTAL / 4;
    const size_t stride = (size_t)gridDim.x * blockDim.x;
    for (size_t idx = (size_t)blockIdx.x * blockDim.x + threadIdx.x; idx < n4;
         idx += stride) {
        float4 v = out[idx];
        v.x -= mx; v.y -= mx; v.z -= mx; v.w -= mx;
        out[idx] = v;
    }
}

extern "C" void kernel_launch(void* const* d_in, const int* in_sizes, int n_in,
                              void* d_out, int out_size, void* d_ws, size_t ws_size,
                              hipStream_t stream) {
    const float* D = (const float*)d_in[0];
    float* out = (float*)d_out;      // holds Rf after K1, logit after K2
    float* Rb = (float*)d_ws;        // 64 MB backward DP result
    float* partial = Rb + TOTAL;     // 2048 floats
    float* maxp = partial + 2048;    // 1 float

    dp_kernel<<<128, 64, 0, stream>>>(D, out, Rb);
    logit_kernel<<<2048, 256, 0, stream>>>((const float4*)D, (const float4*)Rb,
                                           (float4*)out, partial);
    finalmax_kernel<<<1, 256, 0, stream>>>(partial, 2048, maxp);
    sub_kernel<<<2048, 256, 0, stream>>>((float4*)out, maxp);
}